// Round 1
// baseline (510.310 us; speedup 1.0000x reference)
//
#include <hip/hip_runtime.h>
#include <stdint.h>

#define H 16
#define DK 64
#define QL 1024
#define KT 2048
#define DM 1024
#define BATCH 2

typedef __attribute__((ext_vector_type(4))) float f32x4;
typedef __attribute__((ext_vector_type(8))) short s16x8;

enum { EPI_K = 0, EPI_V = 1, EPI_QUV = 2, EPI_P = 3, EPI_OUT = 4 };

__device__ __forceinline__ unsigned short f2bf(float f) {
  union { float f; uint32_t u; } v; v.f = f;
  uint32_t u = v.u;
  u += 0x7fffu + ((u >> 16) & 1u);   // RNE
  return (unsigned short)(u >> 16);
}
__device__ __forceinline__ float bf2f(unsigned short s) {
  union { uint32_t u; float f; } v; v.u = ((uint32_t)s) << 16;
  return v.f;
}

#define MFMA_BF16(A, B, C) __builtin_amdgcn_mfma_f32_16x16x32_bf16((A), (B), (C), 0, 0, 0)

__device__ __forceinline__ void gld_lds16(const void* g, void* l) {
  __builtin_amdgcn_global_load_lds(
      (const __attribute__((address_space(1))) void*)g,
      (__attribute__((address_space(3))) void*)l, 16, 0, 0);
}

// ---------------- prep kernels ----------------

__global__ __launch_bounds__(256) void cast_kv_kernel(
    const float* __restrict__ mem, const float* __restrict__ keyx,
    unsigned short* __restrict__ kv) {
  size_t i4 = (size_t)blockIdx.x * blockDim.x + threadIdx.x;
  if (i4 >= (size_t)BATCH * KT * DM / 4) return;
  size_t e = i4 * 4;
  int b = (int)(e >> 21);
  int rem = (int)(e & ((1u << 21) - 1));
  int j = rem >> 10;
  int d = rem & 1023;
  const float* src = (j < 1024)
      ? (mem + ((size_t)b << 20) + ((size_t)j << 10) + d)
      : (keyx + ((size_t)b << 20) + ((size_t)(j - 1024) << 10) + d);
  float4 v = *(const float4*)src;
  ushort4 o;
  o.x = f2bf(v.x); o.y = f2bf(v.y); o.z = f2bf(v.z); o.w = f2bf(v.w);
  *(ushort4*)(kv + e) = o;
}

__global__ __launch_bounds__(256) void cast4_kernel(
    const float* __restrict__ src, unsigned short* __restrict__ dst, int n4) {
  int i4 = blockIdx.x * blockDim.x + threadIdx.x;
  if (i4 >= n4) return;
  float4 v = *(const float4*)(src + (size_t)i4 * 4);
  ushort4 o;
  o.x = f2bf(v.x); o.y = f2bf(v.y); o.z = f2bf(v.z); o.w = f2bf(v.w);
  *(ushort4*)(dst + (size_t)i4 * 4) = o;
}

__global__ __launch_bounds__(256) void transpose_cast_kernel(
    const float* __restrict__ w0, const float* __restrict__ w1,
    const float* __restrict__ w2, const float* __restrict__ w3,
    const float* __restrict__ w4,
    unsigned short* __restrict__ o0, unsigned short* __restrict__ o1,
    unsigned short* __restrict__ o2, unsigned short* __restrict__ o3,
    unsigned short* __restrict__ o4) {
  __shared__ float tile[32][33];
  const float* src; unsigned short* dst;
  switch (blockIdx.z) {
    case 0: src = w0; dst = o0; break;
    case 1: src = w1; dst = o1; break;
    case 2: src = w2; dst = o2; break;
    case 3: src = w3; dst = o3; break;
    default: src = w4; dst = o4; break;
  }
  int bx = blockIdx.x * 32, by = blockIdx.y * 32;
  int tx = threadIdx.x;   // 0..31
  int ty = threadIdx.y;   // 0..7
#pragma unroll
  for (int r = 0; r < 4; ++r)
    tile[ty + r * 8][tx] = src[(size_t)(by + ty + r * 8) * DM + bx + tx];
  __syncthreads();
#pragma unroll
  for (int r = 0; r < 4; ++r)
    dst[(size_t)(bx + ty + r * 8) * DM + by + tx] = f2bf(tile[tx][ty + r * 8]);
}

__global__ __launch_bounds__(256) void pack_mask_kernel(
    const int* __restrict__ mask, unsigned long long* __restrict__ bits) {
  int t = blockIdx.x * blockDim.x + threadIdx.x;
  int wid = t >> 6, lane = t & 63;
  int v = mask[(size_t)wid * 64 + lane];
  unsigned long long bb = __ballot(v != 0);
  if (lane == 0) bits[wid] = bb;
}

// ---------------- GEMM: C[m][n] = sum_k A[m][k] * B[n][k]  (both row-major, K-contig) ----------------

__global__ __launch_bounds__(256) void gemm_nt_kernel(
    const unsigned short* __restrict__ A, const unsigned short* __restrict__ B,
    int K, int mode,
    unsigned short* __restrict__ out0, unsigned short* __restrict__ out1,
    float* __restrict__ outf,
    const float* __restrict__ uvec, const float* __restrict__ vvec) {
  __shared__ __align__(16) unsigned short lds[128 * 64 * 2];  // A tile + B tile
  char* As = (char*)lds;
  char* Bs = (char*)lds + 128 * 64 * 2;

  const int tid = threadIdx.x;
  const int w = tid >> 6, lane = tid & 63;
  const int g = lane >> 4, l15 = lane & 15;
  const int m0 = blockIdx.y * 128, n0 = blockIdx.x * 128;
  const int wm = w >> 1, wn = w & 1;

  f32x4 zf = {0.f, 0.f, 0.f, 0.f};
  f32x4 acc[4][4];
#pragma unroll
  for (int a = 0; a < 4; ++a)
#pragma unroll
    for (int c = 0; c < 4; ++c) acc[a][c] = zf;

  for (int kt = 0; kt < K; kt += 64) {
#pragma unroll
    for (int q = 0; q < 4; ++q) {
      int o = (w * 4 + q) * 1024 + lane * 16;   // byte offset in tile
      int row = o >> 7;
      int slot = (o & 127) >> 4;
      int ks = slot ^ (row & 7);                // pre-swizzled global source
      gld_lds16(A + (size_t)(m0 + row) * K + kt + ks * 8, As + o);
      gld_lds16(B + (size_t)(n0 + row) * K + kt + ks * 8, Bs + o);
    }
    asm volatile("s_waitcnt vmcnt(0)" ::: "memory");
    __syncthreads();
#pragma unroll
    for (int kk = 0; kk < 2; ++kk) {
      s16x8 af[4], bfr[4];
#pragma unroll
      for (int mf = 0; mf < 4; ++mf) {
        int row = wm * 64 + mf * 16 + l15;
        af[mf] = *(const s16x8*)(As + row * 128 + ((kk * 64 + g * 16) ^ ((row & 7) << 4)));
      }
#pragma unroll
      for (int nf = 0; nf < 4; ++nf) {
        int row = wn * 64 + nf * 16 + l15;
        bfr[nf] = *(const s16x8*)(Bs + row * 128 + ((kk * 64 + g * 16) ^ ((row & 7) << 4)));
      }
#pragma unroll
      for (int mf = 0; mf < 4; ++mf)
#pragma unroll
        for (int nf = 0; nf < 4; ++nf)
          acc[mf][nf] = MFMA_BF16(af[mf], bfr[nf], acc[mf][nf]);
    }
    __syncthreads();
  }

#pragma unroll
  for (int mf = 0; mf < 4; ++mf) {
#pragma unroll
    for (int nf = 0; nf < 4; ++nf) {
#pragma unroll
      for (int i = 0; i < 4; ++i) {
        int m = m0 + wm * 64 + mf * 16 + g * 4 + i;
        int n = n0 + wn * 64 + nf * 16 + l15;
        float val = acc[mf][nf][i];
        if (mode == EPI_K) {
          int b = m >> 11, j = m & 2047, hh = n >> 6, d = n & 63;
          out0[(((size_t)(b * H + hh) * KT + j) << 6) + d] = f2bf(val);
        } else if (mode == EPI_V) {  // swapped roles: m=(h,d), n=(b,j)
          int hh = m >> 6, d = m & 63, b = n >> 11, j = n & 2047;
          out0[((size_t)(b * H + hh) * 64 + d) * KT + j] = f2bf(val);
        } else if (mode == EPI_QUV) {
          int b = m >> 10, i2 = m & 1023, hh = n >> 6, d = n & 63;
          size_t idx = ((size_t)(b * H + hh) * QL + i2) * 64 + d;
          out0[idx] = f2bf(val + uvec[n]);
          out1[idx] = f2bf(val + vvec[n]);
        } else if (mode == EPI_P) {
          int hh = n >> 6, d = n & 63;
          out0[(((size_t)hh * KT + m) << 6) + d] = f2bf(val);
        } else {  // EPI_OUT: fp32
          outf[(size_t)m * DM + n] = val;
        }
      }
    }
  }
}

// ---------------- fused relative attention ----------------
// grid (QL/64, H, B), block 256 = 4 independent waves, each owns 16 q-rows.

__global__ __launch_bounds__(256) void attn_kernel(
    const unsigned short* __restrict__ Qu, const unsigned short* __restrict__ Qv,
    const unsigned short* __restrict__ Kp, const unsigned short* __restrict__ Vt,
    const unsigned short* __restrict__ Pp,
    const unsigned long long* __restrict__ mbits,
    float* __restrict__ aw, unsigned short* __restrict__ cv) {
  __shared__ __align__(16) unsigned short smem[12288];  // 16KB ring (4 waves) + 8KB plds
  const int w = threadIdx.x >> 6, lane = threadIdx.x & 63;
  const int g = lane >> 4, l15 = lane & 15;
  const int b = blockIdx.z, h = blockIdx.y;
  const int r0 = blockIdx.x * 64 + w * 16;
  const int bh = b * H + h;

  const unsigned short* Qu_b = Qu + (size_t)bh * QL * 64;
  const unsigned short* Qv_b = Qv + (size_t)bh * QL * 64;
  const unsigned short* Kp_b = Kp + (size_t)bh * KT * 64;
  const unsigned short* Vt_b = Vt + (size_t)bh * 64 * KT;
  const unsigned short* Pp_b = Pp + (size_t)h * KT * 64;
  float* aw_b = aw + (size_t)bh * QL * KT;
  const unsigned long long* mb_b = mbits + (size_t)b * QL * 32;

  char* ring = (char*)smem + w * 4096;          // [2 parities][16 rows][128B], XOR-swizzled
  char* plds = (char*)smem + 16384 + w * 2048;  // [16 rows][128B], XOR-swizzled

  s16x8 zv = {0, 0, 0, 0, 0, 0, 0, 0};
  s16x8 qu[2], qv[2], qvp[2];
  {
    int r = r0 + l15;
#pragma unroll
    for (int kk = 0; kk < 2; ++kk) {
      qu[kk] = *(const s16x8*)(Qu_b + (size_t)r * 64 + kk * 32 + g * 8);
      qv[kk] = *(const s16x8*)(Qv_b + (size_t)r * 64 + kk * 32 + g * 8);
    }
    int rp = r0 + 1 + l15;
    if (rp < QL) {
#pragma unroll
      for (int kk = 0; kk < 2; ++kk)
        qvp[kk] = *(const s16x8*)(Qv_b + (size_t)rp * 64 + kk * 32 + g * 8);
    } else {
      qvp[0] = zv; qvp[1] = zv;
    }
  }

  f32x4 zf = {0.f, 0.f, 0.f, 0.f};
  const int cfirst = (1008 - r0) >> 6;

  // BDraw chunk (aligned 64 t-columns) into ring[parity].
  // t<=2047: BDraw[r][t]; t==2048: 0; t>=2049: BDraw[r+1][t-2049]  (2048 is 64-aligned -> no mixed chunk)
  auto compute_chunk = [&](int c) {
    const int T = c << 6;
    const bool wrap = (T >= KT);
    f32x4 bd[4];
#pragma unroll
    for (int nf = 0; nf < 4; ++nf) bd[nf] = zf;
#pragma unroll
    for (int kk = 0; kk < 2; ++kk) {
      const s16x8 a = wrap ? qvp[kk] : qv[kk];
#pragma unroll
      for (int nf = 0; nf < 4; ++nf) {
        int t = T + nf * 16 + l15;
        int prow = wrap ? (t - (KT + 1)) : t;
        s16x8 pb = zv;
        if (prow >= 0 && prow < KT)
          pb = *(const s16x8*)(Pp_b + (size_t)prow * 64 + kk * 32 + g * 8);
        bd[nf] = MFMA_BF16(a, pb, bd[nf]);
      }
    }
    char* dst = ring + (c & 1) * 2048;
#pragma unroll
    for (int nf = 0; nf < 4; ++nf)
#pragma unroll
      for (int i = 0; i < 4; ++i) {
        int rr = g * 4 + i;
        *(unsigned short*)(dst + rr * 128 + (((nf * 16 + l15) * 2) ^ ((rr & 7) << 4))) =
            f2bf(bd[nf][i]);
      }
  };

  // one j-step: advance ring, QK^T MFMA, assemble masked e/8
  auto step_e = [&](int s, float (&e)[4][4]) {
    const int j0 = s * 64;
    compute_chunk(cfirst + 1 + s);
    f32x4 acc[4];
#pragma unroll
    for (int nf = 0; nf < 4; ++nf) acc[nf] = zf;
#pragma unroll
    for (int kk = 0; kk < 2; ++kk) {
#pragma unroll
      for (int nf = 0; nf < 4; ++nf) {
        int j = j0 + nf * 16 + l15;
        s16x8 kb = *(const s16x8*)(Kp_b + (size_t)j * 64 + kk * 32 + g * 8);
        acc[nf] = MFMA_BF16(qu[kk], kb, acc[nf]);
      }
    }
    asm volatile("s_waitcnt lgkmcnt(0)" ::: "memory");
#pragma unroll
    for (int i = 0; i < 4; ++i) {
      int rr = g * 4 + i;
      unsigned long long mw = mb_b[(size_t)(r0 + rr) * 32 + s];
#pragma unroll
      for (int nf = 0; nf < 4; ++nf) {
        int j = j0 + nf * 16 + l15;
        int t = j + 1023 - (r0 + rr);
        float bdv = bf2f(*(const unsigned short*)(
            ring + ((t >> 6) & 1) * 2048 + rr * 128 + (((t & 63) * 2) ^ ((rr & 7) << 4))));
        float ev = (acc[nf][i] + bdv) * 0.125f;
        ev = ((mw >> (j & 63)) & 1ull) ? ev : -1e30f;
        e[nf][i] = ev;
      }
    }
  };

  // ---- pass 1: row max + sum ----
  float mrow[4], lrow[4];
#pragma unroll
  for (int i = 0; i < 4; ++i) { mrow[i] = -1e30f; lrow[i] = 0.f; }

  compute_chunk(cfirst);
  for (int s = 0; s < 32; ++s) {
    float e[4][4];
    step_e(s, e);
#pragma unroll
    for (int i = 0; i < 4; ++i) {
      float tmax = fmaxf(fmaxf(e[0][i], e[1][i]), fmaxf(e[2][i], e[3][i]));
#pragma unroll
      for (int d2 = 8; d2 > 0; d2 >>= 1) tmax = fmaxf(tmax, __shfl_xor(tmax, d2));
      float mnew = fmaxf(mrow[i], tmax);
      float ssum = __expf(e[0][i] - mnew) + __expf(e[1][i] - mnew) +
                   __expf(e[2][i] - mnew) + __expf(e[3][i] - mnew);
#pragma unroll
      for (int d2 = 8; d2 > 0; d2 >>= 1) ssum += __shfl_xor(ssum, d2);
      lrow[i] = lrow[i] * __expf(mrow[i] - mnew) + ssum;
      mrow[i] = mnew;
    }
  }

  // ---- pass 2: write aw + PV ----
  f32x4 accO[4];
#pragma unroll
  for (int df = 0; df < 4; ++df) accO[df] = zf;
  float rl[4];
#pragma unroll
  for (int i = 0; i < 4; ++i) rl[i] = 1.f / lrow[i];

  compute_chunk(cfirst);
  for (int s = 0; s < 32; ++s) {
    const int j0 = s * 64;
    float e[4][4];
    step_e(s, e);
#pragma unroll
    for (int i = 0; i < 4; ++i) {
      int rr = g * 4 + i;
#pragma unroll
      for (int nf = 0; nf < 4; ++nf) {
        float p = __expf(e[nf][i] - mrow[i]) * rl[i];
        int j = j0 + nf * 16 + l15;
        aw_b[(size_t)(r0 + rr) * KT + j] = p;
        *(unsigned short*)(plds + rr * 128 + (((nf * 16 + l15) * 2) ^ ((rr & 7) << 4))) = f2bf(p);
      }
    }
    asm volatile("s_waitcnt lgkmcnt(0)" ::: "memory");
#pragma unroll
    for (int kk = 0; kk < 2; ++kk) {
      s16x8 pa = *(const s16x8*)(plds + l15 * 128 + ((kk * 64 + g * 16) ^ ((l15 & 7) << 4)));
#pragma unroll
      for (int df = 0; df < 4; ++df) {
        int d = df * 16 + l15;
        s16x8 vb = *(const s16x8*)(Vt_b + (size_t)d * KT + j0 + kk * 32 + g * 8);
        accO[df] = MFMA_BF16(pa, vb, accO[df]);
      }
    }
  }

#pragma unroll
  for (int df = 0; df < 4; ++df)
#pragma unroll
    for (int i = 0; i < 4; ++i) {
      int r = r0 + g * 4 + i;
      int d = df * 16 + l15;
      cv[((size_t)b * QL + r) * DM + h * 64 + d] = f2bf(accO[df][i]);
    }
}

// ---------------- launch ----------------

extern "C" void kernel_launch(void* const* d_in, const int* in_sizes, int n_in,
                              void* d_out, int out_size, void* d_ws, size_t ws_size,
                              hipStream_t stream) {
  const float* key_x  = (const float*)d_in[0];
  const float* query  = (const float*)d_in[1];
  const float* memory = (const float*)d_in[2];
  const float* pose   = (const float*)d_in[3];
  const int*   mask   = (const int*)d_in[4];
  const float* u      = (const float*)d_in[5];
  const float* v      = (const float*)d_in[6];
  const float* w_key  = (const float*)d_in[7];
  const float* w_val  = (const float*)d_in[8];
  const float* w_qry  = (const float*)d_in[9];
  const float* w_pos  = (const float*)d_in[10];
  const float* w_out  = (const float*)d_in[11];

  char* ws = (char*)d_ws;
  const size_t MB = 1024 * 1024;
  unsigned short* kv_b  = (unsigned short*)(ws + 0);        // [2][2048][1024] bf16  (8MB)
  unsigned short* q_b   = (unsigned short*)(ws + 8 * MB);   // [2][1024][1024]       (4MB)
  unsigned short* pos_b = (unsigned short*)(ws + 12 * MB);  // [2048][1024]          (4MB)
  unsigned short* wk_t  = (unsigned short*)(ws + 16 * MB);
  unsigned short* wv_t  = (unsigned short*)(ws + 18 * MB);
  unsigned short* wq_t  = (unsigned short*)(ws + 20 * MB);
  unsigned short* wp_t  = (unsigned short*)(ws + 22 * MB);
  unsigned short* wo_t  = (unsigned short*)(ws + 24 * MB);
  unsigned short* Kp    = (unsigned short*)(ws + 26 * MB);  // [2][16][2048][64]     (8MB)
  unsigned short* Vt    = (unsigned short*)(ws + 34 * MB);  // [2][16][64][2048]     (8MB)
  unsigned short* Qu    = (unsigned short*)(ws + 42 * MB);  // [2][16][1024][64]     (4MB)
  unsigned short* Qv    = (unsigned short*)(ws + 46 * MB);  // [2][16][1024][64]     (4MB)
  unsigned short* Pp    = (unsigned short*)(ws + 50 * MB);  // [16][2048][64]        (4MB)
  unsigned short* cvb   = (unsigned short*)(ws + 54 * MB);  // [2][1024][1024]       (4MB)
  unsigned long long* mb = (unsigned long long*)(ws + 58 * MB);  // [2][1024][32]    (0.5MB)

  float* out_cv = (float*)d_out;
  float* out_aw = (float*)d_out + (size_t)BATCH * QL * DM;

  cast_kv_kernel<<<4096, 256, 0, stream>>>(memory, key_x, kv_b);
  cast4_kernel<<<2048, 256, 0, stream>>>(query, q_b, BATCH * QL * DM / 4);
  cast4_kernel<<<2048, 256, 0, stream>>>(pose, pos_b, KT * DM / 4);
  transpose_cast_kernel<<<dim3(32, 32, 5), dim3(32, 8), 0, stream>>>(
      w_key, w_val, w_qry, w_pos, w_out, wk_t, wv_t, wq_t, wp_t, wo_t);
  pack_mask_kernel<<<16384, 256, 0, stream>>>(mask, mb);

  // K-proj: A=kv (M=4096), B=wk_t (N=1024)
  gemm_nt_kernel<<<dim3(8, 32), 256, 0, stream>>>(kv_b, wk_t, 1024, EPI_K, Kp, nullptr, nullptr, nullptr, nullptr);
  // V-proj transposed: A=wv_t (M=1024), B=kv (N=4096)
  gemm_nt_kernel<<<dim3(32, 8), 256, 0, stream>>>(wv_t, kv_b, 1024, EPI_V, Vt, nullptr, nullptr, nullptr, nullptr);
  // Q-proj (+u, +v): A=q (M=2048), B=wq_t
  gemm_nt_kernel<<<dim3(8, 16), 256, 0, stream>>>(q_b, wq_t, 1024, EPI_QUV, Qu, Qv, nullptr, u, v);
  // P-proj: A=pos (M=2048), B=wp_t
  gemm_nt_kernel<<<dim3(8, 16), 256, 0, stream>>>(pos_b, wp_t, 1024, EPI_P, Pp, nullptr, nullptr, nullptr, nullptr);

  attn_kernel<<<dim3(16, 16, 2), 256, 0, stream>>>(Qu, Qv, Kp, Vt, Pp, mb, out_aw, cvb);

  // out-proj: A=cv (M=2048), B=wo_t, fp32 out
  gemm_nt_kernel<<<dim3(8, 16), 256, 0, stream>>>(cvb, wo_t, 1024, EPI_OUT, nullptr, nullptr, out_cv, nullptr, nullptr);
}